// Round 8
// baseline (546.642 us; speedup 1.0000x reference)
//
#include <hip/hip_runtime.h>
#include <stdint.h>

// ForceGrid: 10M weighted particles -> 256^3 float grid.
//
// Round-13 structure: SINGLE-PASS direct global atomics (structural probe).
//
// Evidence trail: the LDS-staging counting-sort (R2-R7) is stuck at
// k3 ~91us + k4 ~60us vs a ~60us traffic floor. Four theories (load
// latency R4, store shape R5, atomic-result latency R6, barrier domains
// R7) all neutral or regressions -- the structure itself is the cost.
// This round measures the never-benched alternative:
//   - memset grid (67 MB, ~12us)
//   - fg_atomic: read 160MB inputs via nontemporal float4 loads (keep L2
//     clean for the grid), one fire-and-forget global_atomic_add_f32 per
//     in-bounds particle. Grid (67MB) is Infinity-Cache-resident -> RMWs
//     execute against MALL lines; HBM ~= 160R + ~134 grid fill/writeback.
//   - fp32 add atomics without return have no waitcnt dependency -> kernel
//     is read-BW-bound IF scattered-atomic throughput keeps up (the one
//     unknown this probe prices).
//
// Numerics (bit-exact index math vs the XLA-folded reference; DO NOT change):
//   fi = fl32((p + 10.0f) * 12.75f)   // 12.75f == fl32(1/fl32(20/255))
//   i  = (int32)fl32(fi + 0.5f)       // trunc toward zero, NO FMA contraction
// flat = (ix<<16)|(iy<<8)|iz == (ix*256+iy)*256+iz (row-major, matches ref).
// Accumulation order nondeterminism: same class as all passing rounds.

constexpr int GRID_N = 256;

typedef float f32x4 __attribute__((ext_vector_type(4)));

__device__ __forceinline__ int particle_flat(float px, float py, float pz) {
#pragma clang fp contract(off)
    float fix = (px + 10.0f) * 12.75f;
    float fiy = (py + 10.0f) * 12.75f;
    float fiz = (pz + 10.0f) * 12.75f;
    int ix = (int)(fix + 0.5f);
    int iy = (int)(fiy + 0.5f);
    int iz = (int)(fiz + 0.5f);
    bool in = (ix >= 0) & (ix < GRID_N) &
              (iy >= 0) & (iy < GRID_N) &
              (iz >= 0) & (iz < GRID_N);
    return in ? ((ix << 16) | (iy << 8) | iz) : -1;
}

// ---- single-pass scatter: 4 particles/thread, grid-stride, NT input loads ---
__global__ __launch_bounds__(256) void fg_atomic(const float* __restrict__ pos,
                                                 const float* __restrict__ wgt,
                                                 float* __restrict__ grid,
                                                 int n)
{
    const f32x4* p4 = (const f32x4*)pos;
    const f32x4* w4 = (const f32x4*)wgt;
    int ngroups = n >> 2;
    int G = gridDim.x * 256;
    for (int g = blockIdx.x * 256 + threadIdx.x; g < ngroups; g += G) {
        f32x4 a = __builtin_nontemporal_load(p4 + (size_t)g * 3 + 0);
        f32x4 b = __builtin_nontemporal_load(p4 + (size_t)g * 3 + 1);
        f32x4 c = __builtin_nontemporal_load(p4 + (size_t)g * 3 + 2);
        f32x4 w = __builtin_nontemporal_load(w4 + g);
        int f0 = particle_flat(a.x, a.y, a.z);
        int f1 = particle_flat(a.w, b.x, b.y);
        int f2 = particle_flat(b.z, b.w, c.x);
        int f3 = particle_flat(c.y, c.z, c.w);
        // fire-and-forget fp32 adds: no return value -> no waitcnt dependency
        if (f0 >= 0) atomicAdd(&grid[f0], w.x);
        if (f1 >= 0) atomicAdd(&grid[f1], w.y);
        if (f2 >= 0) atomicAdd(&grid[f2], w.z);
        if (f3 >= 0) atomicAdd(&grid[f3], w.w);
    }
    // tail (n % 4 particles): one thread
    if (blockIdx.x == 0 && threadIdx.x == 0) {
        for (int p = n & ~3; p < n; ++p) {
            int f = particle_flat(pos[3 * p], pos[3 * p + 1], pos[3 * p + 2]);
            if (f >= 0) atomicAdd(&grid[f], wgt[p]);
        }
    }
}

extern "C" void kernel_launch(void* const* d_in, const int* in_sizes, int n_in,
                              void* d_out, int out_size, void* d_ws, size_t ws_size,
                              hipStream_t stream)
{
    const float* pos = (const float*)d_in[0];   // [N,3]
    const float* wgt = (const float*)d_in[1];   // [N]
    float* grid = (float*)d_out;                // [256^3]
    int n = in_sizes[0] / 3;                    // 10,000,000

    // zero the output (harness poisons it); memsetAsync is graph-capturable
    // (the harness itself enqueues hipMemsetAsync in its reset path).
    (void)hipMemsetAsync(grid, 0, (size_t)out_size * sizeof(float), stream);

    int ngroups = (n + 3) / 4;
    int blocks = (ngroups + 255) / 256;
    if (blocks > 2048) blocks = 2048;           // grid-stride the rest
    if (blocks < 1) blocks = 1;
    fg_atomic<<<blocks, 256, 0, stream>>>(pos, wgt, grid, n);
}